// Round 2
// baseline (118.317 us; speedup 1.0000x reference)
//
#include <hip/hip_runtime.h>
#include <hip/hip_bf16.h>

#define N_    16
#define IC_   512
#define OC_   512
#define SDIM_ 512
#define H_    32
#define W_    32
#define HW_   1024

#define FC_SCALER 0.04419417382415922f          /* 1/sqrt(512) */
#define WS_       0.014731391274719738f         /* 1/sqrt(4608) */
#define WS2_      (1.0f/4608.0f)

typedef __attribute__((__ext_vector_type__(8)))  __bf16 bf16x8;
typedef __attribute__((__ext_vector_type__(16))) float  f32x16;
typedef __attribute__((__ext_vector_type__(4)))  int    i32x4;

typedef __attribute__((address_space(1))) const unsigned int GInt;
typedef __attribute__((address_space(3))) unsigned int LInt;

__device__ __forceinline__ unsigned short f2bf(float f) {
    unsigned int u = __builtin_bit_cast(unsigned int, f);
    unsigned int r = (u + 0x7FFFu + ((u >> 16) & 1u)) >> 16;
    return (unsigned short)r;
}

// ---------------- K1: mod[n][c] = style[n]·fcw[c]*FC_SCALER + fcb[c] + 1 ----------------
__global__ void k_mod(const float* __restrict__ style, const float* __restrict__ fcw,
                      const float* __restrict__ fcb, float* __restrict__ mod) {
    int gid = blockIdx.x * blockDim.x + threadIdx.x;
    int wid = gid >> 6, lane = gid & 63;
    if (wid >= N_ * IC_) return;
    int n = wid >> 9, c = wid & 511;
    const float4* sp = (const float4*)(style + n * SDIM_);
    const float4* wp = (const float4*)(fcw + (size_t)c * SDIM_);
    float acc = 0.f;
    for (int i = lane; i < SDIM_ / 4; i += 64) {
        float4 a = sp[i], b = wp[i];
        acc += a.x*b.x + a.y*b.y + a.z*b.z + a.w*b.w;
    }
#pragma unroll
    for (int off = 32; off; off >>= 1) acc += __shfl_xor(acc, off);
    if (lane == 0) mod[wid] = acc * FC_SCALER + fcb[c] + 1.0f;
}

// ---------------- K2: wt2 chunked k-major: [tap][octg4][icc8][kslot8][ocl128][8ic] -------
//                  wsq[oc][ic] = sum_t w^2
__global__ void k_wprep(const float* __restrict__ w, unsigned short* __restrict__ wt,
                        float* __restrict__ wsq) {
    int tid = blockIdx.x * blockDim.x + threadIdx.x;   // 0 .. OC*IC-1
    int oc = tid >> 9, ic = tid & 511;
    int og = oc >> 7, ocl = oc & 127;
    int icc = ic >> 6, k6 = ic & 63, ks = k6 >> 3, i8 = k6 & 7;
    float s = 0.f;
#pragma unroll
    for (int t = 0; t < 9; t++) {
        float v = w[(size_t)tid * 9 + t];
        s += v * v;
        size_t off = ((((size_t)t * 4 + og) * 8 + icc) * 8192)
                   + (size_t)ks * 1024 + ocl * 8 + i8;
        wt[off] = f2bf(v);
    }
    wsq[tid] = s;
}

// ---------------- K3: demod_ws[n][oc] = WS * rsqrt(WS2*sum_ic mod^2*wsq + 1e-8) ---------
__global__ void k_demod(const float* __restrict__ mod, const float* __restrict__ wsq,
                        float* __restrict__ demod_ws) {
    int gid = blockIdx.x * blockDim.x + threadIdx.x;
    int wid = gid >> 6, lane = gid & 63;
    if (wid >= N_ * OC_) return;
    int n = wid >> 9, oc = wid & 511;
    const float4* mp = (const float4*)(mod + n * IC_);
    const float4* qp = (const float4*)(wsq + (size_t)oc * IC_);
    float acc = 0.f;
    for (int i = lane; i < IC_ / 4; i += 64) {
        float4 m = mp[i], q = qp[i];
        acc += m.x*m.x*q.x + m.y*m.y*q.y + m.z*m.z*q.z + m.w*m.w*q.w;
    }
#pragma unroll
    for (int off = 32; off; off >>= 1) acc += __shfl_xor(acc, off);
    if (lane == 0) {
        float s = WS2_ * acc + 1e-8f;
        demod_ws[wid] = WS_ / sqrtf(s);
    }
}

// ---------------- K4: xm chunked k-major: [n][icc8][y32][kslot8][x32][8ic] (bf16) -------
__global__ void k_premod(const float* __restrict__ x, const float* __restrict__ mod,
                         unsigned short* __restrict__ xm) {
    __shared__ __align__(16) unsigned short t_lds[64][80];
    int bx = blockIdx.x;                 // n(16) * hwt(16) * ict(8)
    int n = bx >> 7, hwt = (bx >> 3) & 15, ict = bx & 7;
    int hw0 = hwt * 64, ic0 = ict * 64;
    int tid = threadIdx.x, lane = tid & 63, ty = tid >> 6;
#pragma unroll
    for (int jj = 0; jj < 16; jj++) {
        int icl = ty * 16 + jj;
        float v = x[(size_t)(n * IC_ + ic0 + icl) * HW_ + hw0 + lane]
                  * mod[n * IC_ + ic0 + icl];
        t_lds[lane][icl] = f2bf(v);
    }
    __syncthreads();
    int xcol = tid & 31, ks = tid >> 5;             // ks 0..7
#pragma unroll
    for (int rep = 0; rep < 2; rep++) {
        int hwl = rep * 32 + xcol;
        i32x4 v = *(const i32x4*)&t_lds[hwl][ks * 8];
        int y = (hw0 >> 5) + rep;
        size_t off = ((((size_t)n * 8 + ict) * 32 + y) * 8 + ks) * 256 + xcol * 8;
        *(i32x4*)(xm + off) = v;
    }
}

// ---------------- K5: implicit-GEMM conv, bf16 MFMA 32x32x16 ----------------------------
// block: 128 oc x 256 sp (8 rows), 256 thr = 4 waves; wave tile 128oc x 64sp (2 rows).
// LDS k-major conflict-free; all staging via global_load_lds width=16.
__global__ __launch_bounds__(256, 1)
void k_conv(const unsigned short* __restrict__ xm, const unsigned short* __restrict__ wt,
            const float* __restrict__ demod_ws, float* __restrict__ out) {
    __shared__ __align__(16) unsigned short xt[2][10 * 2048];  // 10 rows x 4KB, x2 = 80KB
    __shared__ __align__(16) unsigned short wb[2][8192];       // 16KB x2
    __shared__ __align__(16) float zslot[4];
    __shared__ float s_demod[128];

    int bx = blockIdx.x;                     // octg(2b)<<6 | n(4b)<<2 | spt(2b)
    int octg = bx >> 6, n = (bx >> 2) & 15, spt = bx & 3;
    int oc0 = octg * 128, y0 = spt * 8;
    int tid = threadIdx.x, lane = tid & 63, wid = tid >> 6;
    int l31 = lane & 31, lhi = lane >> 5;

    if (tid < 128) s_demod[tid] = demod_ws[n * OC_ + oc0 + tid];
    if (tid == 0) { zslot[0] = 0.f; zslot[1] = 0.f; zslot[2] = 0.f; zslot[3] = 0.f; }
    // zero OOB halo rows (persist across icc; loads never touch them)
    if (spt == 0) {
        i32x4 z = {};
        *(i32x4*)&xt[0][tid * 8] = z;
        *(i32x4*)&xt[1][tid * 8] = z;
    }
    if (spt == 3) {
        i32x4 z = {};
        *(i32x4*)&xt[0][9 * 2048 + tid * 8] = z;
        *(i32x4*)&xt[1][9 * 2048 + tid * 8] = z;
    }

    const unsigned short* xsrc_n = xm + (size_t)n * (8 * 32 * 2048);

    auto stage_x = [&](int buf, int icc) {
        for (int wl = wid; wl < 40; wl += 4) {        // 10 rows x 4 loads
            int rr = wl >> 2, j = wl & 3;
            int y = y0 - 1 + rr;
            if ((unsigned)y < 32u) {
                const unsigned short* g =
                    xsrc_n + ((size_t)icc * 32 + y) * 2048 + j * 512 + lane * 8;
                unsigned short* l = &xt[buf][rr * 2048 + j * 512];
                __builtin_amdgcn_global_load_lds((GInt*)g, (LInt*)l, 16, 0, 0);
            }
        }
    };
    auto stage_w = [&](int buf, int tap, int icc) {
        const unsigned short* wsrcc = wt + (((size_t)tap * 4 + octg) * 8 + icc) * 8192;
        for (int wl = wid; wl < 16; wl += 4) {
            const unsigned short* g = wsrcc + wl * 512 + lane * 8;
            unsigned short* l = &wb[buf][wl * 512];
            __builtin_amdgcn_global_load_lds((GInt*)g, (LInt*)l, 16, 0, 0);
        }
    };

    f32x16 acc[4][2] = {};

    stage_x(0, 0);
    stage_w(0, 0, 0);
    __syncthreads();

    int xb = 0, wcur = 0;
#pragma unroll 1
    for (int icc = 0; icc < 8; icc++) {
#pragma unroll 1
        for (int t = 0; t < 9; t++) {
            if (t == 0 && icc < 7) stage_x(xb ^ 1, icc + 1);
            if (t < 8)              stage_w(wcur ^ 1, t + 1, icc);
            else if (icc < 7)       stage_w(wcur ^ 1, 0, icc + 1);

            int dy = t / 3, dx = t % 3;
            const unsigned short* wbp = wb[wcur];
            const unsigned short* xtp = xt[xb];
#pragma unroll
            for (int kk = 0; kk < 4; kk++) {
                int kslot = kk * 2 + lhi;
                bf16x8 af[4], bfr[2];
#pragma unroll
                for (int fo = 0; fo < 4; fo++)
                    af[fo] = *(const bf16x8*)(wbp + kslot * 1024 + (fo * 32 + l31) * 8);
#pragma unroll
                for (int fs = 0; fs < 2; fs++) {
                    int rr = wid * 2 + fs + dy;
                    unsigned cp = (unsigned)(l31 + dx) - 1u;
                    const unsigned short* p = (cp < 32u)
                        ? (xtp + rr * 2048 + kslot * 256 + cp * 8)
                        : (const unsigned short*)zslot;
                    bfr[fs] = *(const bf16x8*)p;
                }
#pragma unroll
                for (int fo = 0; fo < 4; fo++)
#pragma unroll
                    for (int fs = 0; fs < 2; fs++)
                        acc[fo][fs] = __builtin_amdgcn_mfma_f32_32x32x16_bf16(
                            af[fo], bfr[fs], acc[fo][fs], 0, 0, 0);
            }
            __syncthreads();
            wcur ^= 1;
        }
        xb ^= 1;
    }

    // ---- epilogue: scale by demod*WS, store fp32 NCHW ----
#pragma unroll
    for (int fo = 0; fo < 4; fo++) {
#pragma unroll
        for (int fs = 0; fs < 2; fs++) {
            int y = y0 + wid * 2 + fs;
#pragma unroll
            for (int r = 0; r < 16; r++) {
                int row = (r & 3) + 8 * (r >> 2) + 4 * lhi;
                int ocl = fo * 32 + row;
                float v = acc[fo][fs][r] * s_demod[ocl];
                out[((size_t)(n * OC_ + oc0 + ocl) * H_ + y) * W_ + l31] = v;
            }
        }
    }
}

extern "C" void kernel_launch(void* const* d_in, const int* in_sizes, int n_in,
                              void* d_out, int out_size, void* d_ws, size_t ws_size,
                              hipStream_t stream) {
    const float* x      = (const float*)d_in[0];
    const float* style  = (const float*)d_in[1];
    const float* weight = (const float*)d_in[2];
    const float* fcw    = (const float*)d_in[3];
    const float* fcb    = (const float*)d_in[4];
    float* out = (float*)d_out;

    char* ws = (char*)d_ws;
    float*          mod   = (float*)ws;                          // 32 KB
    float*          demod = (float*)(ws + 32768);                // 32 KB
    float*          wsq   = (float*)(ws + 65536);                // 1 MB
    unsigned short* wtb   = (unsigned short*)(ws + 65536 + 1048576);           // 4.5 MB
    unsigned short* xmb   = (unsigned short*)(ws + 65536 + 1048576 + 4718592); // 16 MB

    k_mod   <<<2048, 256, 0, stream>>>(style, fcw, fcb, mod);
    k_wprep <<<1024, 256, 0, stream>>>(weight, wtb, wsq);
    k_demod <<<2048, 256, 0, stream>>>(mod, wsq, demod);
    k_premod<<<2048, 256, 0, stream>>>(x, mod, xmb);
    k_conv  <<<256,  256, 0, stream>>>(xmb, wtb, demod, out);
}

// Round 3
// 105.721 us; speedup vs baseline: 1.1191x; 1.1191x over previous
//
#include <hip/hip_runtime.h>
#include <hip/hip_bf16.h>

#define N_    16
#define IC_   512
#define OC_   512
#define SDIM_ 512
#define H_    32
#define W_    32
#define HW_   1024

#define FC_SCALER 0.04419417382415922f          /* 1/sqrt(512) */
#define WS_       0.014731391274719738f         /* 1/sqrt(4608) */
#define WS2_      (1.0f/4608.0f)

typedef __attribute__((__ext_vector_type__(8)))  __bf16 bf16x8;
typedef __attribute__((__ext_vector_type__(16))) float  f32x16;
typedef __attribute__((__ext_vector_type__(4)))  int    i32x4;

typedef __attribute__((address_space(1))) const unsigned int GInt;
typedef __attribute__((address_space(3))) unsigned int LInt;

#define WAIT4()  asm volatile("s_waitcnt vmcnt(4)"  ::: "memory")
#define WAIT14() asm volatile("s_waitcnt vmcnt(14)" ::: "memory")
#define WAIT0()  asm volatile("s_waitcnt vmcnt(0)"  ::: "memory")

__device__ __forceinline__ unsigned short f2bf(float f) {
    unsigned int u = __builtin_bit_cast(unsigned int, f);
    unsigned int r = (u + 0x7FFFu + ((u >> 16) & 1u)) >> 16;
    return (unsigned short)r;
}

// ---------------- K1: mod[n][c] = style[n]·fcw[c]*FC_SCALER + fcb[c] + 1 ----------------
__global__ void k_mod(const float* __restrict__ style, const float* __restrict__ fcw,
                      const float* __restrict__ fcb, float* __restrict__ mod) {
    int gid = blockIdx.x * blockDim.x + threadIdx.x;
    int wid = gid >> 6, lane = gid & 63;
    if (wid >= N_ * IC_) return;
    int n = wid >> 9, c = wid & 511;
    const float4* sp = (const float4*)(style + n * SDIM_);
    const float4* wp = (const float4*)(fcw + (size_t)c * SDIM_);
    float acc = 0.f;
    for (int i = lane; i < SDIM_ / 4; i += 64) {
        float4 a = sp[i], b = wp[i];
        acc += a.x*b.x + a.y*b.y + a.z*b.z + a.w*b.w;
    }
#pragma unroll
    for (int off = 32; off; off >>= 1) acc += __shfl_xor(acc, off);
    if (lane == 0) mod[wid] = acc * FC_SCALER + fcb[c] + 1.0f;
}

// ---------------- K2: wt chunked k-major: [tap][octg4][icc8][ks8][ocl128][8ic] ----------
__global__ void k_wprep(const float* __restrict__ w, unsigned short* __restrict__ wt,
                        float* __restrict__ wsq) {
    int tid = blockIdx.x * blockDim.x + threadIdx.x;   // 0 .. OC*IC-1
    int oc = tid >> 9, ic = tid & 511;
    int og = oc >> 7, ocl = oc & 127;
    int icc = ic >> 6, k6 = ic & 63, ks = k6 >> 3, i8 = k6 & 7;
    float s = 0.f;
#pragma unroll
    for (int t = 0; t < 9; t++) {
        float v = w[(size_t)tid * 9 + t];
        s += v * v;
        size_t off = ((((size_t)t * 4 + og) * 8 + icc) * 8192)
                   + (size_t)ks * 1024 + ocl * 8 + i8;
        wt[off] = f2bf(v);
    }
    wsq[tid] = s;
}

// ---------------- K3: demod_ws[n][oc] = WS * rsqrt(WS2*sum_ic mod^2*wsq + 1e-8) ---------
__global__ void k_demod(const float* __restrict__ mod, const float* __restrict__ wsq,
                        float* __restrict__ demod_ws) {
    int gid = blockIdx.x * blockDim.x + threadIdx.x;
    int wid = gid >> 6, lane = gid & 63;
    if (wid >= N_ * OC_) return;
    int n = wid >> 9, oc = wid & 511;
    const float4* mp = (const float4*)(mod + n * IC_);
    const float4* qp = (const float4*)(wsq + (size_t)oc * IC_);
    float acc = 0.f;
    for (int i = lane; i < IC_ / 4; i += 64) {
        float4 m = mp[i], q = qp[i];
        acc += m.x*m.x*q.x + m.y*m.y*q.y + m.z*m.z*q.z + m.w*m.w*q.w;
    }
#pragma unroll
    for (int off = 32; off; off >>= 1) acc += __shfl_xor(acc, off);
    if (lane == 0) {
        float s = WS2_ * acc + 1e-8f;
        demod_ws[wid] = WS_ / sqrtf(s);
    }
}

// ---------------- K4: xm chunked k-major: [n][icc8][y32][ks8][x32][8ic] (bf16) ----------
__global__ void k_premod(const float* __restrict__ x, const float* __restrict__ mod,
                         unsigned short* __restrict__ xm) {
    __shared__ __align__(16) unsigned short t_lds[64][80];
    int bx = blockIdx.x;                 // n(16) * hwt(16) * ict(8)
    int n = bx >> 7, hwt = (bx >> 3) & 15, ict = bx & 7;
    int hw0 = hwt * 64, ic0 = ict * 64;
    int tid = threadIdx.x, lane = tid & 63, ty = tid >> 6;
#pragma unroll
    for (int jj = 0; jj < 16; jj++) {
        int icl = ty * 16 + jj;
        float v = x[(size_t)(n * IC_ + ic0 + icl) * HW_ + hw0 + lane]
                  * mod[n * IC_ + ic0 + icl];
        t_lds[lane][icl] = f2bf(v);
    }
    __syncthreads();
    int xcol = tid & 31, ks = tid >> 5;             // ks 0..7
#pragma unroll
    for (int rep = 0; rep < 2; rep++) {
        int hwl = rep * 32 + xcol;
        i32x4 v = *(const i32x4*)&t_lds[hwl][ks * 8];
        int y = (hw0 >> 5) + rep;
        size_t off = ((((size_t)n * 8 + ict) * 32 + y) * 8 + ks) * 256 + xcol * 8;
        *(i32x4*)(xm + off) = v;
    }
}

// ---------------- K5: implicit-GEMM conv, bf16 MFMA 32x32x16 ----------------------------
// grid 256 = octg(4) x n(16) x spt(4). Block: 128 oc x 256 sp (8 rows), 4 waves.
// Wave tile: 64 oc (M=2) x 128 sp = 4 rows (N=4) -> 0.75 LDS reads per MFMA.
// x tile: [10 rows][ks8][col32][16B] double-buffered; weights rolling-3 per tap.
// All staging via global_load_lds(16B); counted vmcnt + raw barriers (T3/T4), setprio (T5).
__global__ __launch_bounds__(256, 1)
void k_conv(const unsigned short* __restrict__ xm, const unsigned short* __restrict__ wt,
            const float* __restrict__ demod_ws, float* __restrict__ out) {
    __shared__ __align__(16) unsigned short xt[2][10 * 2048];   // 40KB x2
    __shared__ __align__(16) unsigned short wb[3][8192];        // 16KB x3
    __shared__ __align__(16) unsigned short trash[512];         // 1KB dummy-load target
    __shared__ __align__(16) float zslot[4];
    __shared__ float s_demod[128];

    int bx = blockIdx.x;
    int octg = bx >> 6, n = (bx >> 2) & 15, spt = bx & 3;
    int oc0 = octg * 128, y0 = spt * 8;
    int tid = threadIdx.x, lane = tid & 63, wid = tid >> 6;
    int l31 = lane & 31, lhi = lane >> 5;
    int wr = wid >> 1, wc = wid & 1;     // wr: oc half, wc: row half (4 rows each)

    // prologue scalar load first so its implicit vmcnt drain precedes staging issues
    if (tid < 128) s_demod[tid] = demod_ws[n * OC_ + oc0 + tid];
    __builtin_amdgcn_sched_barrier(0);

    if (tid == 0) { i32x4 z = {}; *(i32x4*)zslot = z; }
    if (spt == 0) {           // image row y0-1 = -1 -> xt row 0 stays zero
        i32x4 z = {};
        *(i32x4*)&xt[0][tid * 8] = z;
        *(i32x4*)&xt[1][tid * 8] = z;
    }
    if (spt == 3) {           // image row y0+8 = 32 -> xt row 9 stays zero
        i32x4 z = {};
        *(i32x4*)&xt[0][9 * 2048 + tid * 8] = z;
        *(i32x4*)&xt[1][9 * 2048 + tid * 8] = z;
    }

    const unsigned short* xsrc_n = xm + (size_t)n * (8 * 32 * 2048);

    // 10 rows x 4 chunks of 1KB; OOB rows load into trash (uniform vmcnt count = 10/wave)
    auto stage_x = [&](int buf, int icc) {
        for (int wl = wid; wl < 40; wl += 4) {
            int rr = wl >> 2, q = wl & 3;
            int y = y0 - 1 + rr;
            int yc = y < 0 ? 0 : (y > 31 ? 31 : y);
            bool oob = (unsigned)y >= 32u;
            const unsigned short* g =
                xsrc_n + ((size_t)icc * 32 + yc) * 2048 + q * 512 + lane * 8;
            unsigned short* l = oob ? (unsigned short*)trash
                                    : &xt[buf][rr * 2048 + q * 512];
            __builtin_amdgcn_global_load_lds((GInt*)g, (LInt*)l, 16, 0, 0);
        }
    };
    // 16KB tap tile = 16 chunks of 1KB, 4 per wave
    auto stage_w = [&](int slot, int tap, int icc) {
        const unsigned short* wsrcc = wt + (((size_t)tap * 4 + octg) * 8 + icc) * 8192;
#pragma unroll
        for (int k = 0; k < 4; k++) {
            int wl = wid + k * 4;
            const unsigned short* g = wsrcc + wl * 512 + lane * 8;
            unsigned short* l = &wb[slot][wl * 512];
            __builtin_amdgcn_global_load_lds((GInt*)g, (LInt*)l, 16, 0, 0);
        }
    };

    f32x16 acc[2][4] = {};

    stage_x(0, 0);            // x before w0: w0-done implies x-done (in-order vmcnt)
    stage_w(0, 0, 0);
    stage_w(1, 1, 0);
    asm volatile("s_waitcnt lgkmcnt(0)" ::: "memory");   // zero-fills + s_demod visible

    int xb = 0;
#pragma unroll 1
    for (int icc = 0; icc < 8; icc++) {
#pragma unroll
        for (int t = 0; t < 9; t++) {
            // ---- counted wait: w(T) landed (T issued 2 taps ago) ----
            if (t == 1 || t == 2) { if (icc < 7) WAIT14(); else WAIT4(); }
            else if (icc == 7 && t == 8) WAIT0();
            else WAIT4();
            __builtin_amdgcn_s_barrier();
            // ---- issue w(T+2) into slot (t+2)%3 ----
            {
                int tt = t + 2;
                int wicc = icc + (tt >= 9);
                int wtap = tt >= 9 ? tt - 9 : tt;
                if (wicc < 8) stage_w((t + 2) % 3, wtap, wicc);
            }
            // ---- issue next icc's x tile (3 taps of flight before forced at t=3) ----
            if (t == 0 && icc < 7) stage_x(xb ^ 1, icc + 1);

            // ---- compute ----
            const int dy = t / 3, dx = t % 3;
            const unsigned short* wbp = wb[t % 3];
            const unsigned short* xtp = xt[xb];
            int colbase = l31 + dx - 1;
            bool oobc = (unsigned)colbase >= 32u;
#pragma unroll
            for (int kk = 0; kk < 4; kk++) {
                int ks = kk * 2 + lhi;
                bf16x8 af[2], bfr[4];
#pragma unroll
                for (int fo = 0; fo < 2; fo++)
                    af[fo] = *(const bf16x8*)(wbp + ks * 1024 + (wr * 64 + fo * 32 + l31) * 8);
#pragma unroll
                for (int fs = 0; fs < 4; fs++) {
                    int rr = wc * 4 + fs + dy;
                    const unsigned short* p = oobc
                        ? (const unsigned short*)zslot
                        : (xtp + rr * 2048 + ks * 256 + colbase * 8);
                    bfr[fs] = *(const bf16x8*)p;
                }
                __builtin_amdgcn_s_setprio(1);
#pragma unroll
                for (int fo = 0; fo < 2; fo++)
#pragma unroll
                    for (int fs = 0; fs < 4; fs++)
                        acc[fo][fs] = __builtin_amdgcn_mfma_f32_32x32x16_bf16(
                            af[fo], bfr[fs], acc[fo][fs], 0, 0, 0);
                __builtin_amdgcn_s_setprio(0);
            }
        }
        xb ^= 1;
    }

    // ---- epilogue: scale by demod*WS, store fp32 NCHW ----
#pragma unroll
    for (int fo = 0; fo < 2; fo++) {
#pragma unroll
        for (int fs = 0; fs < 4; fs++) {
            int y = y0 + wc * 4 + fs;
#pragma unroll
            for (int r = 0; r < 16; r++) {
                int row = (r & 3) + 8 * (r >> 2) + 4 * lhi;
                int ocl = wr * 64 + fo * 32 + row;
                float v = acc[fo][fs][r] * s_demod[ocl];
                out[((size_t)(n * OC_ + oc0 + ocl) * H_ + y) * W_ + l31] = v;
            }
        }
    }
}

extern "C" void kernel_launch(void* const* d_in, const int* in_sizes, int n_in,
                              void* d_out, int out_size, void* d_ws, size_t ws_size,
                              hipStream_t stream) {
    const float* x      = (const float*)d_in[0];
    const float* style  = (const float*)d_in[1];
    const float* weight = (const float*)d_in[2];
    const float* fcw    = (const float*)d_in[3];
    const float* fcb    = (const float*)d_in[4];
    float* out = (float*)d_out;

    char* ws = (char*)d_ws;
    float*          mod   = (float*)ws;                          // 32 KB
    float*          demod = (float*)(ws + 32768);                // 32 KB
    float*          wsq   = (float*)(ws + 65536);                // 1 MB
    unsigned short* wtb   = (unsigned short*)(ws + 65536 + 1048576);           // 4.5 MB
    unsigned short* xmb   = (unsigned short*)(ws + 65536 + 1048576 + 4718592); // 16 MB

    k_mod   <<<2048, 256, 0, stream>>>(style, fcw, fcb, mod);
    k_wprep <<<1024, 256, 0, stream>>>(weight, wtb, wsq);
    k_demod <<<2048, 256, 0, stream>>>(mod, wsq, demod);
    k_premod<<<2048, 256, 0, stream>>>(x, mod, xmb);
    k_conv  <<<256,  256, 0, stream>>>(xmb, wtb, demod, out);
}

// Round 4
// 98.503 us; speedup vs baseline: 1.2012x; 1.0733x over previous
//
#include <hip/hip_runtime.h>
#include <hip/hip_bf16.h>

#define N_    16
#define IC_   512
#define OC_   512
#define SDIM_ 512
#define H_    32
#define W_    32
#define HW_   1024

#define FC_SCALER 0.04419417382415922f          /* 1/sqrt(512) */
#define WS_       0.014731391274719738f         /* 1/sqrt(4608) */
#define WS2_      (1.0f/4608.0f)

typedef __attribute__((__ext_vector_type__(8)))  __bf16 bf16x8;
typedef __attribute__((__ext_vector_type__(16))) float  f32x16;
typedef __attribute__((__ext_vector_type__(4)))  int    i32x4;

typedef __attribute__((address_space(1))) const unsigned int GInt;
typedef __attribute__((address_space(3))) unsigned int LInt;

#define WAIT0()  asm volatile("s_waitcnt vmcnt(0)"  ::: "memory")
#define WAIT3()  asm volatile("s_waitcnt vmcnt(3)"  ::: "memory")

__device__ __forceinline__ unsigned short f2bf(float f) {
    unsigned int u = __builtin_bit_cast(unsigned int, f);
    unsigned int r = (u + 0x7FFFu + ((u >> 16) & 1u)) >> 16;
    return (unsigned short)r;
}

// ---------------- K1: mod[n][c] = style[n]·fcw[c]*FC_SCALER + fcb[c] + 1 ----------------
__global__ void k_mod(const float* __restrict__ style, const float* __restrict__ fcw,
                      const float* __restrict__ fcb, float* __restrict__ mod) {
    int gid = blockIdx.x * blockDim.x + threadIdx.x;
    int wid = gid >> 6, lane = gid & 63;
    if (wid >= N_ * IC_) return;
    int n = wid >> 9, c = wid & 511;
    const float4* sp = (const float4*)(style + n * SDIM_);
    const float4* wp = (const float4*)(fcw + (size_t)c * SDIM_);
    float acc = 0.f;
    for (int i = lane; i < SDIM_ / 4; i += 64) {
        float4 a = sp[i], b = wp[i];
        acc += a.x*b.x + a.y*b.y + a.z*b.z + a.w*b.w;
    }
#pragma unroll
    for (int off = 32; off; off >>= 1) acc += __shfl_xor(acc, off);
    if (lane == 0) mod[wid] = acc * FC_SCALER + fcb[c] + 1.0f;
}

// ---------------- K2: wt k-major: [tap][octg4][icc16][ks4][ocl128][8ic] -----------------
__global__ void k_wprep(const float* __restrict__ w, unsigned short* __restrict__ wt,
                        float* __restrict__ wsq) {
    int tid = blockIdx.x * blockDim.x + threadIdx.x;   // 0 .. OC*IC-1
    int oc = tid >> 9, ic = tid & 511;
    int og = oc >> 7, ocl = oc & 127;
    int icc = ic >> 5, ks = (ic >> 3) & 3, i8 = ic & 7;
    float s = 0.f;
#pragma unroll
    for (int t = 0; t < 9; t++) {
        float v = w[(size_t)tid * 9 + t];
        s += v * v;
        size_t off = ((((size_t)t * 4 + og) * 16 + icc) * 4 + ks) * 1024
                   + (size_t)ocl * 8 + i8;
        wt[off] = f2bf(v);
    }
    wsq[tid] = s;
}

// ---------------- K3: demod_ws[n][oc] = WS * rsqrt(WS2*sum_ic mod^2*wsq + 1e-8) ---------
__global__ void k_demod(const float* __restrict__ mod, const float* __restrict__ wsq,
                        float* __restrict__ demod_ws) {
    int gid = blockIdx.x * blockDim.x + threadIdx.x;
    int wid = gid >> 6, lane = gid & 63;
    if (wid >= N_ * OC_) return;
    int n = wid >> 9, oc = wid & 511;
    const float4* mp = (const float4*)(mod + n * IC_);
    const float4* qp = (const float4*)(wsq + (size_t)oc * IC_);
    float acc = 0.f;
    for (int i = lane; i < IC_ / 4; i += 64) {
        float4 m = mp[i], q = qp[i];
        acc += m.x*m.x*q.x + m.y*m.y*q.y + m.z*m.z*q.z + m.w*m.w*q.w;
    }
#pragma unroll
    for (int off = 32; off; off >>= 1) acc += __shfl_xor(acc, off);
    if (lane == 0) {
        float s = WS2_ * acc + 1e-8f;
        demod_ws[wid] = WS_ / sqrtf(s);
    }
}

// ---------------- K4: xm k-major: [n][icc16][y32][ks4][x32][8ic] (bf16) -----------------
__global__ void k_premod(const float* __restrict__ x, const float* __restrict__ mod,
                         unsigned short* __restrict__ xm) {
    __shared__ __align__(16) unsigned short t_lds[64][80];
    int bx = blockIdx.x;                 // n(16) * hwt(16) * ict(8)
    int n = bx >> 7, hwt = (bx >> 3) & 15, ict = bx & 7;
    int hw0 = hwt * 64, ic0 = ict * 64;
    int tid = threadIdx.x, lane = tid & 63, ty = tid >> 6;
#pragma unroll
    for (int jj = 0; jj < 16; jj++) {
        int icl = ty * 16 + jj;
        float v = x[(size_t)(n * IC_ + ic0 + icl) * HW_ + hw0 + lane]
                  * mod[n * IC_ + ic0 + icl];
        t_lds[lane][icl] = f2bf(v);
    }
    __syncthreads();
    int xcol = tid & 31, ks64 = tid >> 5;           // ks64 0..7 within the 64-ic block
    int icc = ict * 2 + (ks64 >> 2), ks = ks64 & 3;
#pragma unroll
    for (int rep = 0; rep < 2; rep++) {
        int hwl = rep * 32 + xcol;
        i32x4 v = *(const i32x4*)&t_lds[hwl][ks64 * 8];
        int y = (hw0 >> 5) + rep;
        size_t off = ((((size_t)n * 16 + icc) * 32 + y) * 4 + ks) * 256 + xcol * 8;
        *(i32x4*)(xm + off) = v;
    }
}

// ---------------- K5: implicit-GEMM conv, bf16 MFMA 32x32x16 ----------------------------
// grid 256 (octg4 x n16 x spt4), block 512thr = 8 waves (wr2 x wc2 x kh2) -> 2 waves/SIMD.
// Block tile 128oc x 256sp (8 rows); wave tile 64oc x 128sp x 16ic-of-32 (kh k-split).
// dx-major tap phases: per phase load 6 x-row frags once (r6), reuse across dy and fs.
// icc = 32-ic chunks (16). LDS: xt dbuf 2x20KB + wb 2 sets x 24KB = 88KB. Counted vmcnt.
__global__ __launch_bounds__(512, 2)
void k_conv(const unsigned short* __restrict__ xm, const unsigned short* __restrict__ wt,
            const float* __restrict__ demod_ws, float* __restrict__ out) {
    __shared__ __align__(16) char smem[40960 + 49152 + 1024 + 32 + 512];
    // carve: xt[2] @0 (2x20KB), wb[2] @40960 (2x24KB), trash @90112 (1KB),
    //        zslot @91136 (16B used), s_demod @91168+ (512B)
    unsigned short* xt0   = (unsigned short*)(smem);
    unsigned short* wb0   = (unsigned short*)(smem + 40960);
    unsigned short* trash = (unsigned short*)(smem + 90112);
    float*          zslot = (float*)(smem + 91136);
    float*          s_demod = (float*)(smem + 91168);

    int bx = blockIdx.x;
    // XCD-swizzle: blocks on the same XCD (bx%8 pairs) share octg -> wt L2 locality
    int x8 = bx & 7;
    int octg = x8 >> 1;
    int r    = ((bx >> 3) << 1) | (x8 & 1);     // 0..63
    int n = r >> 2, spt = r & 3;
    int oc0 = octg * 128, y0 = spt * 8;

    int tid = threadIdx.x, lane = tid & 63, wid = tid >> 6;
    int l31 = lane & 31, lhi = lane >> 5;
    int wr = wid & 1, wc = (wid >> 1) & 1, kh = wid >> 2;

    // prologue scalar staging first; fence so its implicit vmcnt drain precedes issues
    if (tid < 128) s_demod[tid] = demod_ws[n * OC_ + oc0 + tid];
    __builtin_amdgcn_sched_barrier(0);

    if (tid == 0) { i32x4 z = {}; *(i32x4*)zslot = z; }
    // pre-zero OOB halo rows of both x buffers (loads for them go to trash)
    if (spt == 0 && tid < 128) {
        i32x4 z = {};
        *(i32x4*)&xt0[tid * 8] = z;                       // buf0 row 0 (2KB)
        *(i32x4*)&xt0[10240 + tid * 8] = z;               // buf1 row 0
    }
    if (spt == 3 && tid < 128) {
        i32x4 z = {};
        *(i32x4*)&xt0[9 * 1024 + tid * 8] = z;            // buf0 row 9
        *(i32x4*)&xt0[10240 + 9 * 1024 + tid * 8] = z;    // buf1 row 9
    }

    const unsigned short* xsrc_n = xm + (size_t)n * (16 * 32 * 1024);

    // x tile: [10 rows][4ks][32col][8ic] = 20KB = 20 chunks of 1KB; pad to 24 (3/wave)
    auto stage_x = [&](int buf, int icc) {
#pragma unroll
        for (int k = 0; k < 3; k++) {
            int c = wid + k * 8;                 // 0..23
            int rr = c >> 1, hh = c & 1;
            int y = y0 - 1 + rr;
            bool oob = (c >= 20) | ((unsigned)y >= 32u) | (icc >= 16);
            int yc = y < 0 ? 0 : (y > 31 ? 31 : y);
            int iccc = icc & 15;
            const unsigned short* g =
                xsrc_n + ((size_t)iccc * 32 + yc) * 1024 + hh * 512 + lane * 8;
            unsigned short* l = oob ? trash
                                    : xt0 + buf * 10240 + rr * 1024 + hh * 512;
            __builtin_amdgcn_global_load_lds((GInt*)g, (LInt*)l, 16, 0, 0);
        }
    };
    // weight set for phase p (taps dy*3+p, dy=0..2), 3x8KB = 24 chunks (3/wave, dy=k)
    auto stage_w = [&](int set, int p, int icc) {
#pragma unroll
        for (int k = 0; k < 3; k++) {
            int tap = k * 3 + p;
            const unsigned short* g =
                wt + ((((size_t)tap * 4 + octg) * 16 + icc) * 4096) + wid * 512 + lane * 8;
            unsigned short* l = wb0 + set * 12288 + k * 4096 + wid * 512;
            __builtin_amdgcn_global_load_lds((GInt*)g, (LInt*)l, 16, 0, 0);
        }
    };

    f32x16 acc[2][4] = {};

    stage_x(0, 0);
    stage_w(0, 0, 0);
    asm volatile("s_waitcnt lgkmcnt(0)" ::: "memory");   // zero-fills + s_demod visible

    int xb = 0;
    int kso = kh * 2 + lhi;                              // per-lane kslot
#pragma unroll 1
    for (int icc = 0; icc < 16; icc++) {
#pragma unroll 1
        for (int p = 0; p < 3; p++) {
            // ---- counted wait: this phase's weight set (and P0: x tile) landed ----
            if (p == 1) WAIT3(); else WAIT0();
            __builtin_amdgcn_s_barrier();
            // ---- issue next phase's weight set; at P0 also next icc's x tile ----
            int g1 = icc * 3 + p + 1;
            if (g1 < 48) stage_w(g1 & 1, g1 % 3, g1 / 3);
            if (p == 0) stage_x(xb ^ 1, icc + 1);        // icc 15 -> all trash

            // ---- compute: r6 once, reuse across dy & fs ----
            const unsigned short* xtb = xt0 + xb * 10240;
            const unsigned short* wbp = wb0 + ((icc * 3 + p) & 1) * 12288;
            int col = l31 + p - 1;
            bool oobc = (unsigned)col >= 32u;
            bf16x8 r6[6];
#pragma unroll
            for (int j = 0; j < 6; j++) {
                int rr = wc * 4 + j;
                const unsigned short* src = oobc ? (const unsigned short*)zslot
                    : xtb + rr * 1024 + kso * 256 + col * 8;
                r6[j] = *(const bf16x8*)src;
            }
#pragma unroll
            for (int dy = 0; dy < 3; dy++) {
                bf16x8 af0 = *(const bf16x8*)(wbp + dy * 4096 + kso * 1024
                                              + (wr * 64 + l31) * 8);
                bf16x8 af1 = *(const bf16x8*)(wbp + dy * 4096 + kso * 1024
                                              + (wr * 64 + 32 + l31) * 8);
                __builtin_amdgcn_s_setprio(1);
#pragma unroll
                for (int fs = 0; fs < 4; fs++)
                    acc[0][fs] = __builtin_amdgcn_mfma_f32_32x32x16_bf16(
                        af0, r6[fs + dy], acc[0][fs], 0, 0, 0);
#pragma unroll
                for (int fs = 0; fs < 4; fs++)
                    acc[1][fs] = __builtin_amdgcn_mfma_f32_32x32x16_bf16(
                        af1, r6[fs + dy], acc[1][fs], 0, 0, 0);
                __builtin_amdgcn_s_setprio(0);
            }
        }
        xb ^= 1;
    }

    // ---- epilogue: combine kh halves via LDS exchange, scale, store fp32 NCHW ----
    __syncthreads();
    float* exch = (float*)smem;                          // 64KB, aliases xt/wb
#pragma unroll
    for (int fo = 0; fo < 2; fo++) {
        if (kh) {
#pragma unroll
            for (int fs = 0; fs < 4; fs++)
#pragma unroll
                for (int rg = 0; rg < 16; rg++)
                    exch[(((wid & 3) * 4 + fs) * 16 + rg) * 64 + lane] = acc[fo][fs][rg];
        }
        __syncthreads();
        if (!kh) {
#pragma unroll
            for (int fs = 0; fs < 4; fs++) {
                int y = y0 + wc * 4 + fs;
#pragma unroll
                for (int rg = 0; rg < 16; rg++) {
                    int row = (rg & 3) + 8 * (rg >> 2) + 4 * lhi;
                    int ocl = wr * 64 + fo * 32 + row;
                    float v = acc[fo][fs][rg]
                            + exch[((wid * 4 + fs) * 16 + rg) * 64 + lane];
                    v *= s_demod[ocl];
                    out[((size_t)(n * OC_ + oc0 + ocl) * H_ + y) * W_ + l31] = v;
                }
            }
        }
        __syncthreads();
    }
}

extern "C" void kernel_launch(void* const* d_in, const int* in_sizes, int n_in,
                              void* d_out, int out_size, void* d_ws, size_t ws_size,
                              hipStream_t stream) {
    const float* x      = (const float*)d_in[0];
    const float* style  = (const float*)d_in[1];
    const float* weight = (const float*)d_in[2];
    const float* fcw    = (const float*)d_in[3];
    const float* fcb    = (const float*)d_in[4];
    float* out = (float*)d_out;

    char* ws = (char*)d_ws;
    float*          mod   = (float*)ws;                          // 32 KB
    float*          demod = (float*)(ws + 32768);                // 32 KB
    float*          wsq   = (float*)(ws + 65536);                // 1 MB
    unsigned short* wtb   = (unsigned short*)(ws + 65536 + 1048576);           // 4.5 MB
    unsigned short* xmb   = (unsigned short*)(ws + 65536 + 1048576 + 4718592); // 16 MB

    k_mod   <<<2048, 256, 0, stream>>>(style, fcw, fcb, mod);
    k_wprep <<<1024, 256, 0, stream>>>(weight, wtb, wsq);
    k_demod <<<2048, 256, 0, stream>>>(mod, wsq, demod);
    k_premod<<<2048, 256, 0, stream>>>(x, mod, xmb);
    k_conv  <<<256,  512, 0, stream>>>(xmb, wtb, demod, out);
}